// Round 1
// baseline (294.341 us; speedup 1.0000x reference)
//
#include <hip/hip_runtime.h>

// Gathered skinny GEMM: out[b, r] = sum_d x[b,d] * w[indices[r], d]
//   x: [32][4096] f32, w: [11008][4096] f32, indices: [4403] i32,
//   out: [32][4403] f32 (einsum 'bsd,rd->bsr', s==1)
//
// HBM-bound (~72 MB gathered weight @ 6.3 TB/s ~= 11.5 us floor; fp32 VALU
// floor 7.3 us). Design: thread-per-row, weight streamed through VGPRs in
// full-cacheline (64B/lane) groups; x read via wave-uniform addresses so the
// compiler emits scalar loads (free broadcast, no LDS). K split 64-ways for
// grid parallelism (1152 blocks), partials merged with one atomicAdd per
// output per block.

#define D_MODEL   4096
#define REMAINED  4403
#define BATCH     32
#define BLOCK     256
#define RTILES    ((REMAINED + BLOCK - 1) / BLOCK)   // 18
#define KSPLIT    64
#define KCHUNK    (D_MODEL / KSPLIT)                 // 64 floats per block
#define K4CHUNK   (KCHUNK / 4)                       // 16 float4 per block
#define GRID      (RTILES * KSPLIT)                  // 1152 blocks

__global__ __launch_bounds__(BLOCK) void gather_gemv(
    const float* __restrict__ x,
    const float* __restrict__ w,
    const int*   __restrict__ idx,
    float*       __restrict__ out)
{
    const int rt = blockIdx.x % RTILES;
    const int ks = blockIdx.x / RTILES;

    const int  r      = rt * BLOCK + (int)threadIdx.x;
    const bool active = (r < REMAINED);
    const int  rc     = active ? r : (REMAINED - 1);
    const int  row    = idx[rc];

    const float4* __restrict__ wrow = (const float4*)(w + (size_t)row * D_MODEL);
    const float4* __restrict__ x4   = (const float4*)x;

    const int k4_0 = ks * K4CHUNK;

    float acc[BATCH];
#pragma unroll
    for (int b = 0; b < BATCH; ++b) acc[b] = 0.f;

    // Each kb group loads 4 consecutive float4 = 64 B per lane = one full
    // cacheline, so the row-divergent gather still uses every fetched byte.
    for (int kb = 0; kb < K4CHUNK / 4; ++kb) {
        float4 wv[4];
#pragma unroll
        for (int u = 0; u < 4; ++u) wv[u] = wrow[k4_0 + kb * 4 + u];

#pragma unroll
        for (int u = 0; u < 4; ++u) {
            const int k4 = k4_0 + kb * 4 + u;
#pragma unroll
            for (int b = 0; b < BATCH; ++b) {
                // b*(D_MODEL/4)+k4 is wave-uniform -> scalar load + broadcast
                const float4 xv = x4[b * (D_MODEL / 4) + k4];
                acc[b] = fmaf(wv[u].x, xv.x, acc[b]);
                acc[b] = fmaf(wv[u].y, xv.y, acc[b]);
                acc[b] = fmaf(wv[u].z, xv.z, acc[b]);
                acc[b] = fmaf(wv[u].w, xv.w, acc[b]);
            }
        }
    }

    if (active) {
#pragma unroll
        for (int b = 0; b < BATCH; ++b)
            atomicAdd(&out[b * REMAINED + r], acc[b]);
    }
}

extern "C" void kernel_launch(void* const* d_in, const int* in_sizes, int n_in,
                              void* d_out, int out_size, void* d_ws, size_t ws_size,
                              hipStream_t stream) {
    const float* x   = (const float*)d_in[0];
    const float* w   = (const float*)d_in[1];
    const int*   idx = (const int*)d_in[2];
    float*       out = (float*)d_out;

    // Harness re-poisons d_out to 0xAA before every timed launch; we
    // accumulate with atomics, so zero it first (memset node is graph-safe).
    hipMemsetAsync(out, 0, (size_t)out_size * sizeof(float), stream);
    gather_gemv<<<GRID, BLOCK, 0, stream>>>(x, w, idx, out);
}